// Round 9
// baseline (128.213 us; speedup 1.0000x reference)
//
#include <hip/hip_runtime.h>
#include <math.h>
#include <limits.h>

// Problem constants (match reference)
#define BD 4
#define ZD 40
#define YD 1024
#define XD 1024
#define BZYX 167772160   // BD*ZD*YD*XD

constexpr int BLOCK = 256;
constexpr unsigned SMALL_LOG = 18;              // 256k slots * 8B = 2 MB
constexpr unsigned SMASK = (1u << SMALL_LOG) - 1;
constexpr size_t BM_BYTES   = (size_t)BZYX / 8;          // 20,971,520
constexpr size_t STAB_BYTES = (size_t)8 << SMALL_LOG;    // 2,097,152

typedef unsigned uvec4 __attribute__((ext_vector_type(4)));

__device__ __forceinline__ unsigned hash_mix(unsigned x) {
    x ^= x >> 16; x *= 0x7feb352dU;
    x ^= x >> 15; x *= 0x846ca68bU;
    x ^= x >> 16;
    return x;
}
__device__ __forceinline__ float smooth_l1(float d) {
    float ad = fabsf(d);
    return (ad < 1.0f) ? 0.5f * d * d : ad - 0.5f;
}
__device__ __forceinline__ float logaddexp0(float l) {
    return (l > 0.0f) ? (l + log1pf(expf(-l))) : log1pf(expf(l));
}

// Tiled bitmap: one 64B cache line = 8z x 8y x 8x block (all dims %8==0).
__device__ __forceinline__ unsigned cell_gid(int b, int z, int y, int x) {
    unsigned line = ((unsigned)(b * (ZD >> 3) + (z >> 3)) * (YD >> 3) + (y >> 3)) * (XD >> 3) + (x >> 3);
    unsigned bit  = ((unsigned)(z & 7) << 6) | ((unsigned)(y & 7) << 3) | (unsigned)(x & 7);
    return (line << 9) | bit;
}
__device__ __forceinline__ bool bm_test(const unsigned* __restrict__ bm, unsigned gid) {
    return (bm[gid >> 5] >> (gid & 31)) & 1u;
}

// R==1 match: 27 bit-tests (~2 cache lines), argmin dL1 with first-k
// tie-break via distance-class masks (k ascending = jnp.argmin order).
__device__ __forceinline__ bool match27(const unsigned* __restrict__ bm,
                                        int b, int z, int y, int x,
                                        int& sz, int& sy, int& sx) {
    const int zc0 = max(z - 1, 0), zc2 = min(z + 1, ZD - 1);
    const int yc0 = max(y - 1, 0), yc2 = min(y + 1, YD - 1);
    const int xc0 = max(x - 1, 0), xc2 = min(x + 1, XD - 1);
    const int zc[3] = {zc0, z, zc2};
    const int yc[3] = {yc0, y, yc2};
    const int xc[3] = {xc0, x, xc2};
    unsigned hm = 0;
#pragma unroll
    for (int a = 0; a < 3; ++a)
#pragma unroll
        for (int c = 0; c < 3; ++c)
#pragma unroll
            for (int d = 0; d < 3; ++d)
                hm |= ((unsigned)bm_test(bm, cell_gid(b, zc[a], yc[c], xc[d]))) << (a * 9 + c * 3 + d);
    constexpr unsigned M0 = 1u << 13;
    constexpr unsigned M1 = (1u << 4) | (1u << 10) | (1u << 12) | (1u << 14) | (1u << 16) | (1u << 22);
    constexpr unsigned M2 = (1u << 1) | (1u << 3) | (1u << 5) | (1u << 7) | (1u << 9) | (1u << 11) |
                            (1u << 15) | (1u << 17) | (1u << 19) | (1u << 21) | (1u << 23) | (1u << 25);
    int bk;
    if (hm & M0)      bk = 13;
    else if (hm & M1) bk = __ffs((int)(hm & M1)) - 1;
    else if (hm & M2) bk = __ffs((int)(hm & M2)) - 1;
    else if (hm)      bk = __ffs((int)hm) - 1;
    else return false;
    const int ai = bk / 9, ci = (bk / 3) % 3, di = bk % 3;
    sz = (ai == 0) ? zc0 : ((ai == 1) ? z : zc2);
    sy = (ci == 0) ? yc0 : ((ci == 1) ? y : yc2);
    sx = (di == 0) ? xc0 : ((di == 1) ? x : xc2);
    return true;
}

__device__ bool matchR(const unsigned* __restrict__ bm, int R,
                       int b, int z, int y, int x, int& sz, int& sy, int& sx) {
    int bestd = INT_MAX; bool m = false;
    for (int dz = -R; dz <= R; ++dz) {
        const int zz = min(max(z + dz, 0), ZD - 1);
        const int adz = abs(dz);
        for (int dy = -R; dy <= R; ++dy) {
            const int yy = min(max(y + dy, 0), YD - 1);
            const int adzy = adz + abs(dy);
            for (int dx = -R; dx <= R; ++dx) {
                const int d = adzy + abs(dx);
                if (d >= bestd) continue;
                const int xx = min(max(x + dx, 0), XD - 1);
                if (bm_test(bm, cell_gid(b, zz, yy, xx))) {
                    bestd = d; m = true; sz = zz; sy = yy; sx = xx;
                }
            }
        }
    }
    return m;
}

// stab encoding (zero-init friendly): entry 0 = empty; key = gid+1 in high 32;
// low 32 = ~row accumulated with atomicMax (max(~row) == min(row); 0 = none).
__device__ __forceinline__ void stab_insert(unsigned long long* stab, unsigned gid) {
    const unsigned long long desired = ((unsigned long long)(gid + 1) << 32);
    unsigned s = hash_mix(gid) & SMASK;
    while (true) {
        unsigned long long old = atomicCAS(&stab[s], 0ull, desired);
        if (old == 0ull || (unsigned)(old >> 32) == gid + 1) return;
        s = (s + 1) & SMASK;
    }
}
__device__ __forceinline__ void stab_minrow(unsigned long long* stab, unsigned gid, unsigned row) {
    unsigned s = hash_mix(gid) & SMASK;
    while (true) {
        const unsigned long long e = stab[s];      // key immutable during scan
        if (e == 0ull) return;                     // cell not selected
        if ((unsigned)(e >> 32) == gid + 1) {
            atomicMax((unsigned*)&stab[s], ~row);  // low half
            return;
        }
        s = (s + 1) & SMASK;
    }
}
__device__ __forceinline__ unsigned stab_getrow(const unsigned long long* stab, unsigned gid) {
    unsigned s = hash_mix(gid) & SMASK;
    while (true) {
        const unsigned long long e = stab[s];
        if ((unsigned)(e >> 32) == gid + 1) return ~((unsigned)e);
        s = (s + 1) & SMASK;
    }
}

// ---- kernel 1: clear bm + stab + counter (nt streaming stores, wide grid) ----
__global__ void k_clear(uvec4* __restrict__ wsv, int n4) {
    const uvec4 z = (uvec4)(0u);
    const int stride = gridDim.x * blockDim.x;
    for (int k = blockIdx.x * blockDim.x + threadIdx.x; k < n4; k += stride)
        __builtin_nontemporal_store(z, &wsv[k]);
}

// ---- kernel 2: bitmap build ----
__global__ void k_build(const int4* __restrict__ li, int Nl,
                        unsigned* __restrict__ bm) {
    const int j = blockIdx.x * blockDim.x + threadIdx.x;
    if (j >= Nl) return;
    int4 v = li[j];  // [b,z,y,x]
    const unsigned gid = cell_gid(v.x, v.y, v.z, v.w);
    atomicOr(&bm[gid >> 5], 1u << (gid & 31));
}

// ---- kernel 3: radar match + occ/cnt/off sums + stab insert ----
__global__ void __launch_bounds__(BLOCK)
k_match(const float4* __restrict__ pf, const float* __restrict__ occ,
        const int4* __restrict__ ri, const unsigned* __restrict__ bm,
        unsigned long long* __restrict__ stab, const int* __restrict__ Rptr,
        int Nr, int* __restrict__ mcell, double* __restrict__ partials) {
    const int R = *Rptr;
    double occ_s = 0.0, cnt_s = 0.0, off_s = 0.0;
    const int stride = gridDim.x * blockDim.x;
    for (int i = blockIdx.x * BLOCK + threadIdx.x; i < Nr; i += stride) {
        int4 rib = ri[i];
        const int b = rib.x, z = rib.y, y = rib.z, x = rib.w;
        int sz = 0, sy = 0, sx = 0;
        const bool matched = (R == 1) ? match27(bm, b, z, y, x, sz, sy, sx)
                                      : matchR(bm, R, b, z, y, x, sz, sy, sx);
        float m = 0.f; int mc = -1;
        if (matched) {
            m = 1.f; cnt_s += 1.0;
            const float4 pp = pf[i];
            off_s += (double)(smooth_l1(pp.x - (float)(sx - x)) +
                              smooth_l1(pp.y - (float)(sy - y)) +
                              smooth_l1(pp.z - (float)(sz - z)));
            const unsigned gid = cell_gid(b, sz, sy, sx);
            stab_insert(stab, gid);
            mc = (int)gid;
        }
        mcell[i] = mc;
        const float lg = occ[i];
        occ_s += (double)(logaddexp0(lg) - lg * m);
    }
    __shared__ double sh[3][BLOCK];
    const int tid = threadIdx.x;
    sh[0][tid] = occ_s; sh[1][tid] = cnt_s; sh[2][tid] = off_s;
    __syncthreads();
    for (int s = BLOCK / 2; s > 0; s >>= 1) {
        if (tid < s) {
            sh[0][tid] += sh[0][tid + s];
            sh[1][tid] += sh[1][tid + s];
            sh[2][tid] += sh[2][tid + s];
        }
        __syncthreads();
    }
    if (tid == 0) {
        partials[blockIdx.x * 4 + 0] = sh[0][0];
        partials[blockIdx.x * 4 + 1] = sh[1][0];
        partials[blockIdx.x * 4 + 2] = sh[2][0];
        partials[blockIdx.x * 4 + 3] = 0.0;
    }
}

// ---- kernel 4: lidar scan (min original row per selected cell) ----
__global__ void k_scan(const int4* __restrict__ li, int Nl,
                       unsigned long long* __restrict__ stab) {
    const int j = blockIdx.x * blockDim.x + threadIdx.x;
    if (j >= Nl) return;
    int4 v = li[j];
    stab_minrow(stab, cell_gid(v.x, v.y, v.z, v.w), (unsigned)j);
}

// ---- kernel 5: feature loss + last-block finalize ----
__global__ void __launch_bounds__(BLOCK)
k_feat(const float* __restrict__ pfw, const int* __restrict__ mcell,
       const unsigned long long* __restrict__ stab, const float* __restrict__ lf,
       int Nr, double* __restrict__ fpart, const double* __restrict__ partials,
       unsigned* __restrict__ counter, int mblk, float* __restrict__ out) {
    double fs = 0.0;
    const int stride = gridDim.x * blockDim.x;
    for (int i = blockIdx.x * BLOCK + threadIdx.x; i < Nr; i += stride) {
        const int mc = mcell[i];
        if (mc >= 0) {
            const unsigned row = stab_getrow(stab, (unsigned)mc);
            fs += (double)fabsf(pfw[(size_t)i * 4 + 3] - lf[(size_t)row * 4 + 3]);
        }
    }
    __shared__ double sh[4][BLOCK];
    __shared__ bool isLast;
    const int tid = threadIdx.x;
    sh[0][tid] = fs;
    __syncthreads();
    for (int s = BLOCK / 2; s > 0; s >>= 1) {
        if (tid < s) sh[0][tid] += sh[0][tid + s];
        __syncthreads();
    }
    if (tid == 0) {
        fpart[blockIdx.x] = sh[0][0];
        __threadfence();
        const unsigned done = atomicAdd(counter, 1u);
        isLast = (done == gridDim.x - 1);
    }
    __syncthreads();
    if (!isLast) return;

    // Last block: final reduce of match partials + feat partials.
    double a0 = 0, a1 = 0, a2 = 0, a3 = 0;
    for (int k = tid; k < mblk; k += BLOCK) {
        a0 += partials[k * 4 + 0];
        a1 += partials[k * 4 + 1];
        a2 += partials[k * 4 + 2];
    }
    for (int k = tid; k < (int)gridDim.x; k += BLOCK) a3 += fpart[k];
    __syncthreads();
    sh[0][tid] = a0; sh[1][tid] = a1; sh[2][tid] = a2; sh[3][tid] = a3;
    __syncthreads();
    for (int s = BLOCK / 2; s > 0; s >>= 1) {
        if (tid < s) {
            sh[0][tid] += sh[0][tid + s];
            sh[1][tid] += sh[1][tid + s];
            sh[2][tid] += sh[2][tid + s];
            sh[3][tid] += sh[3][tid + s];
        }
        __syncthreads();
    }
    if (tid == 0) {
        const double occ_loss = sh[0][0] / (double)Nr;
        const double cnt = sh[1][0];
        const double off_loss = sh[2][0] / fmax(cnt * 3.0, 1.0);
        const double feat_loss = sh[3][0] / fmax(cnt, 1.0);
        out[0] = (float)(0.2 * occ_loss + 1.0 * off_loss + 1.0 * feat_loss);
    }
}

extern "C" void kernel_launch(void* const* d_in, const int* in_sizes, int n_in,
                              void* d_out, int out_size, void* d_ws, size_t ws_size,
                              hipStream_t stream) {
    const float4* pf = (const float4*)d_in[0];   // (Nr,4)
    const float*  oc = (const float*)d_in[1];    // (Nr,1,1)
    const int4*   ri = (const int4*)d_in[2];     // (Nr,4)
    const float*  lf = (const float*)d_in[3];    // (Nl,4)
    const int4*   li = (const int4*)d_in[4];     // (Nl,4)
    const int*    Rp = (const int*)d_in[5];      // scalar (device)

    const int Nr = in_sizes[0] / 4;
    const int Nl = in_sizes[3] / 4;
    const int nblkL = (Nl + BLOCK - 1) / BLOCK;          // 4096
    int nblk = (Nr + BLOCK - 1) / BLOCK;                 // 1024
    if (nblk > 2048) nblk = 2048;                        // grid-stride beyond

    // Workspace layout: [bm][stab][counter] is one contiguous zero region.
    size_t off = 0;
    auto alloc = [&](size_t n) { size_t o = off; off += (n + 255) & ~(size_t)255; return o; };
    char* ws = (char*)d_ws;
    unsigned*           bm      = (unsigned*)(ws + alloc(BM_BYTES));
    unsigned long long* stab    = (unsigned long long*)(ws + alloc(STAB_BYTES));
    unsigned*           counter = (unsigned*)(ws + alloc(256));
    const size_t zeroBytes = off;                        // bm + stab + counter
    int*                mcell = (int*)(ws + alloc((size_t)Nr * 4));
    double*             parts = (double*)(ws + alloc((size_t)nblk * 4 * sizeof(double)));
    double*             fpart = (double*)(ws + alloc((size_t)nblk * sizeof(double)));

    k_clear<<<4096, BLOCK, 0, stream>>>((uvec4*)ws, (int)(zeroBytes / 16));
    k_build<<<nblkL, BLOCK, 0, stream>>>(li, Nl, bm);
    k_match<<<nblk, BLOCK, 0, stream>>>(pf, oc, ri, bm, stab, Rp, Nr, mcell, parts);
    k_scan<<<nblkL, BLOCK, 0, stream>>>(li, Nl, stab);
    k_feat<<<nblk, BLOCK, 0, stream>>>((const float*)pf, mcell, stab, lf, Nr, fpart,
                                       parts, counter, nblk, (float*)d_out);
}